// Round 4
// baseline (803.493 us; speedup 1.0000x reference)
//
#include <hip/hip_runtime.h>
#include <hip/hip_bf16.h>

#define B_  2
#define S_  2048
#define D_  2048
#define H_  16
#define DH_ 128
#define M_  (B_*S_)   // 4096

typedef __hip_bfloat16 bf16;
typedef float v4f __attribute__((ext_vector_type(4)));
typedef short v8s __attribute__((ext_vector_type(8)));

__device__ __forceinline__ short f2s(float x) {
  bf16 h = __float2bfloat16(x);
  return *reinterpret_cast<const short*>(&h);
}
// load 8 contiguous f32 elems, convert to bf16 bits
__device__ __forceinline__ v8s ld8(const float* p) {
  v4f a = *reinterpret_cast<const v4f*>(p);
  v4f b = *reinterpret_cast<const v4f*>(p + 4);
  v8s r = { f2s(a[0]), f2s(a[1]), f2s(a[2]), f2s(a[3]),
            f2s(b[0]), f2s(b[1]), f2s(b[2]), f2s(b[3]) };
  return r;
}
__device__ __forceinline__ void store_out(bf16* p, float v)  { *p = __float2bfloat16(v); }
__device__ __forceinline__ void store_out(float* p, float v) { *p = v; }

// async 16B global->LDS (direct, no VGPR round-trip). LDS dest is
// wave-uniform base + lane*16; global src is per-lane.
__device__ __forceinline__ void gll16(const bf16* g, bf16* l) {
  __builtin_amdgcn_global_load_lds((const __attribute__((address_space(1))) void*)g,
                                   (__attribute__((address_space(3))) void*)l,
                                   16, 0, 0);
}

// streaming f32 -> bf16 convert, 8 elems/thread
__global__ __launch_bounds__(256) void cvt_f32_bf16(const float* __restrict__ in,
                                                    bf16* __restrict__ out, int n8) {
  int i = blockIdx.x * 256 + threadIdx.x;
  if (i >= n8) return;
  *reinterpret_cast<v8s*>(out + (size_t)i * 8) = ld8(in + (size_t)i * 8);
}

// C = A @ W^T + bias ; A [M,K] bf16 row-major, W [N,K] bf16 row-major.
// m97 structure: 128x128 tile, BK=32, global_load_lds width-16 staging
// (round-2 verified: ~458 TF at these shapes).
// MODE 0: QK fused, W=[Wq;Wk] (N=4096). n<2048 -> Q (scaled) else K, both
//         to [B,H,S,dh].
// MODE 2: V -> [B,H,dh,S]  (transposed for PV fragment loads)
// MODE 3: plain [M,N] f32 out (final projection)
template <int MODE, typename TOUT>
__global__ __launch_bounds__(256) void gemm_bt(const bf16* __restrict__ A,
                                               const bf16* __restrict__ W,
                                               const float* __restrict__ bias0,
                                               const float* __restrict__ bias1,
                                               TOUT* __restrict__ out0,
                                               TOUT* __restrict__ out1) {
  __shared__ __align__(16) bf16 As[128 * 32];
  __shared__ __align__(16) bf16 Bs[128 * 32];
  const int tid  = threadIdx.x;
  const int lane = tid & 63, wave = tid >> 6;
  const int wm = wave >> 1, wn = wave & 1;
  const int quad = lane >> 4, l16 = lane & 15;
  const int bm = blockIdx.y * 128, bn = blockIdx.x * 128;

  const bf16* aptr = A + (size_t)(bm + (tid >> 2)) * D_ + (tid & 3) * 8;
  const bf16* bptr = W + (size_t)(bn + (tid >> 2)) * D_ + (tid & 3) * 8;
  bf16* lA0 = As + wave * 512;
  bf16* lA1 = As + 2048 + wave * 512;
  bf16* lB0 = Bs + wave * 512;
  bf16* lB1 = Bs + 2048 + wave * 512;

  v4f acc[4][4] = {};
  for (int k0 = 0; k0 < D_; k0 += 32) {
    gll16(aptr + k0,                    lA0);
    gll16(aptr + (size_t)64 * D_ + k0,  lA1);
    gll16(bptr + k0,                    lB0);
    gll16(bptr + (size_t)64 * D_ + k0,  lB1);
    __syncthreads();
    v8s af[4], bfr[4];
#pragma unroll
    for (int mi = 0; mi < 4; ++mi)
      af[mi] = *reinterpret_cast<const v8s*>(&As[(wm * 64 + mi * 16 + l16) * 32 + quad * 8]);
#pragma unroll
    for (int ni = 0; ni < 4; ++ni)
      bfr[ni] = *reinterpret_cast<const v8s*>(&Bs[(wn * 64 + ni * 16 + l16) * 32 + quad * 8]);
#pragma unroll
    for (int mi = 0; mi < 4; ++mi)
#pragma unroll
      for (int ni = 0; ni < 4; ++ni)
        acc[mi][ni] = __builtin_amdgcn_mfma_f32_16x16x32_bf16(af[mi], bfr[ni], acc[mi][ni], 0, 0, 0);
    __syncthreads();
  }

  constexpr float QSCALE = 0.12752003912f;  // 1/sqrt(128) * log2(e)
  const int proj = (MODE == 0) ? (bn >> 11) : 0;   // block-uniform: 0=Q, 1=K
  const float* bias = proj ? bias1 : bias0;
  TOUT* outp = proj ? out1 : out0;
  const int bnl = bn & 2047;
#pragma unroll
  for (int ni = 0; ni < 4; ++ni) {
    const int nl = bnl + wn * 64 + ni * 16 + l16;   // 0..2047 within projection
    const float bv = bias[nl];
#pragma unroll
    for (int mi = 0; mi < 4; ++mi) {
      const int m0 = bm + wm * 64 + mi * 16 + quad * 4;
#pragma unroll
      for (int r = 0; r < 4; ++r) {
        const int m = m0 + r;           // row m: (b,s). col nl: (h,d)
        float v = acc[mi][ni][r] + bv;
        size_t idx;
        if (MODE == 0) {
          if (!proj) v *= QSCALE;
          int b = m >> 11, s = m & (S_ - 1);
          int h = nl >> 7, d = nl & (DH_ - 1);
          idx = ((size_t)(b * H_ + h) * S_ + s) * DH_ + d;
        } else if (MODE == 2) {
          int b = m >> 11, s = m & (S_ - 1);
          int h = nl >> 7, d = nl & (DH_ - 1);
          idx = ((size_t)(b * H_ + h) * DH_ + d) * S_ + s;
        } else {
          idx = (size_t)m * D_ + nl;
        }
        store_out(outp + idx, v);
      }
    }
  }
}

// Flash attention, causal. Q/K: [B,H,S,dh], Vt: [B,H,dh,S] (all bf16). Out: [B,S,D] bf16.
// Block = 128 Q rows (8 waves x 16 rows), K-tile = 64 keys, 512 threads.
// BARRIER-FREE: K/V fragments are loaded directly from global (the per-(b,h)
// K/V working set is 2 MB -> L2/L3-resident; LDS staging was pure overhead,
// cf. m169). Only per-wave Ps lives in LDS (18 KB). Waves run independently
// with per-wave causal trip counts.
#define QBLK 128
__global__ __launch_bounds__(512, 2) void attn_fused(const bf16* __restrict__ Q,
                                                     const bf16* __restrict__ K,
                                                     const bf16* __restrict__ Vt,
                                                     bf16* __restrict__ Oa) {
  __shared__ __align__(16) bf16 Ps[8][16 * 72];   // per-wave P, padded stride 72
  const int tid  = threadIdx.x;
  const int lane = tid & 63, wave = tid >> 6;
  const int quad = lane >> 4, l16 = lane & 15;
  // longest-first: work per block ~ qt, launch big blocks first.
  const int qt = (int)gridDim.x - 1 - (int)blockIdx.x;
  const int bh = blockIdx.y;
  const int b = bh >> 4, h = bh & 15;
  const bf16* Qh = Q  + (size_t)bh * S_ * DH_;
  const bf16* Kh = K  + (size_t)bh * S_ * DH_;
  const bf16* Vh = Vt + (size_t)bh * DH_ * S_;

  const int qrow0 = qt * QBLK + wave * 16;
  v8s qf[4];
#pragma unroll
  for (int kk = 0; kk < 4; ++kk)
    qf[kk] = *reinterpret_cast<const v8s*>(&Qh[(size_t)(qrow0 + l16) * DH_ + kk * 32 + quad * 8]);

  v4f acc_o[8] = {};
  float m_i[4], l_i[4];
#pragma unroll
  for (int r = 0; r < 4; ++r) { m_i[r] = -1.0e30f; l_i[r] = 0.f; }

  // per-wave causal trip count: last key tile containing key index qrow0+15
  const int ktend = ((qrow0 + 15) >> 6) + 1;
  for (int kt = 0; kt < ktend; ++kt) {
    const int kbase = kt * 64;
    // S = Q K^T (Q pre-scaled by 1/sqrt(dh)*log2e); K frags direct from global
    v4f sc[4];
    __builtin_amdgcn_s_setprio(1);
#pragma unroll
    for (int nt = 0; nt < 4; ++nt) {
      v4f a = {};
#pragma unroll
      for (int kk = 0; kk < 4; ++kk) {
        v8s kf = *reinterpret_cast<const v8s*>(
            &Kh[(size_t)(kbase + nt * 16 + l16) * DH_ + (kk * 4 + quad) * 8]);
        a = __builtin_amdgcn_mfma_f32_16x16x32_bf16(qf[kk], kf, a, 0, 0, 0);
      }
      sc[nt] = a;
    }
    __builtin_amdgcn_s_setprio(0);
    if (kbase + 63 > qrow0) {   // diagonal tile: causal mask
#pragma unroll
      for (int nt = 0; nt < 4; ++nt)
#pragma unroll
        for (int r = 0; r < 4; ++r) {
          int kc2 = kbase + nt * 16 + l16;
          int qr = qrow0 + quad * 4 + r;
          if (kc2 > qr) sc[nt][r] = -1.0e30f;
        }
    }
    // online softmax; C-layout: row = quad*4 + r, col = nt*16 + l16
#pragma unroll
    for (int r = 0; r < 4; ++r) {
      float mx = fmaxf(fmaxf(sc[0][r], sc[1][r]), fmaxf(sc[2][r], sc[3][r]));
      mx = fmaxf(mx, __shfl_xor(mx, 1));
      mx = fmaxf(mx, __shfl_xor(mx, 2));
      mx = fmaxf(mx, __shfl_xor(mx, 4));
      mx = fmaxf(mx, __shfl_xor(mx, 8));
      // T13 defer-max: only rescale when max grew by >8 (log2 domain)
      if (mx > m_i[r] + 8.0f) {
        float alpha = exp2f(m_i[r] - mx);
        m_i[r] = mx;
        l_i[r] *= alpha;
#pragma unroll
        for (int nt8 = 0; nt8 < 8; ++nt8) acc_o[nt8][r] *= alpha;
      }
      const float mm = m_i[r];
      float s0 = exp2f(sc[0][r] - mm);
      float s1 = exp2f(sc[1][r] - mm);
      float s2 = exp2f(sc[2][r] - mm);
      float s3 = exp2f(sc[3][r] - mm);
      sc[0][r] = s0; sc[1][r] = s1; sc[2][r] = s2; sc[3][r] = s3;
      float t = s0 + s1 + s2 + s3;
      t += __shfl_xor(t, 1); t += __shfl_xor(t, 2);
      t += __shfl_xor(t, 4); t += __shfl_xor(t, 8);
      l_i[r] += t;
    }
    // P: C-layout regs -> per-wave LDS (bf16) -> A-layout frags
#pragma unroll
    for (int nt = 0; nt < 4; ++nt)
#pragma unroll
      for (int r = 0; r < 4; ++r)
        Ps[wave][(quad * 4 + r) * 72 + nt * 16 + l16] = __float2bfloat16(sc[nt][r]);
    // own-wave write->read ordering only (DS in-order + compiler lgkmcnt)
    asm volatile("s_waitcnt lgkmcnt(0)" ::: "memory");
    // O += P V ; V frags direct from global
    __builtin_amdgcn_s_setprio(1);
#pragma unroll
    for (int kk2 = 0; kk2 < 2; ++kk2) {
      v8s pf = *reinterpret_cast<const v8s*>(&Ps[wave][l16 * 72 + kk2 * 32 + quad * 8]);
#pragma unroll
      for (int nt8 = 0; nt8 < 8; ++nt8) {
        v8s vf = *reinterpret_cast<const v8s*>(
            &Vh[(size_t)(nt8 * 16 + l16) * S_ + kbase + (kk2 * 4 + quad) * 8]);
        acc_o[nt8] = __builtin_amdgcn_mfma_f32_16x16x32_bf16(pf, vf, acc_o[nt8], 0, 0, 0);
      }
    }
    __builtin_amdgcn_s_setprio(0);
  }

#pragma unroll
  for (int r = 0; r < 4; ++r) {
    const float inv = 1.0f / l_i[r];
    const int srow = qrow0 + quad * 4 + r;
#pragma unroll
    for (int nt8 = 0; nt8 < 8; ++nt8)
      Oa[((size_t)b * S_ + srow) * D_ + h * DH_ + nt8 * 16 + l16] =
          __float2bfloat16(acc_o[nt8][r] * inv);
  }
}

extern "C" void kernel_launch(void* const* d_in, const int* in_sizes, int n_in,
                              void* d_out, int out_size, void* d_ws, size_t ws_size,
                              hipStream_t stream) {
  // Canary: all-zero output (absmax exactly 3.5625) signals a tripped assumption.
  if (n_in != 9 ||
      in_sizes[0] != M_ * D_ ||
      in_sizes[1] != D_ * D_ || in_sizes[2] != D_ ||
      in_sizes[3] != D_ * D_ || in_sizes[4] != D_ ||
      in_sizes[5] != D_ * D_ || in_sizes[6] != D_ ||
      in_sizes[7] != D_ * D_ || in_sizes[8] != D_ ||
      out_size != M_ * D_)
    return;

  const float* x  = (const float*)d_in[0];
  const float* Wq = (const float*)d_in[1];
  const float* bq = (const float*)d_in[2];
  const float* Wk = (const float*)d_in[3];
  const float* bk = (const float*)d_in[4];
  const float* Wv = (const float*)d_in[5];
  const float* bv = (const float*)d_in[6];
  const float* Wo = (const float*)d_in[7];
  const float* bo = (const float*)d_in[8];
  float* out = (float*)d_out;   // OUTPUT IS FLOAT32 (reference output dtype)

  const size_t NT = (size_t)M_ * D_;   // 8388608 elems per tensor
  const size_t WN = (size_t)D_ * D_;   // 4194304 elems per weight
  // Buffer plan:
  //   d_out (33.6 MB f32):  [0,16.8) qws (bf16 Q), [16.8,33.6) x_bf16
  //     both dead before the final GEMM overwrites d_out.
  //   ws (50.3 MB): kws | vtw | aws
  //     Wq||Wk concat (16.8 MB) fills aws before the QK GEMM; Wv reuses
  //     aws[0:8.4) before the V GEMM; aws becomes the attn output after
  //     (weights dead); Wo parks in kws (K dead after attn).
  bf16* qws   = (bf16*)d_out;
  bf16* xbf   = (bf16*)d_out + NT;
  bf16* kws   = (bf16*)d_ws;
  bf16* vtw   = kws + NT;
  bf16* aws   = vtw + NT;
  bf16* wqk   = aws;            // [4096][2048] bf16 concat
  bf16* wv_s  = aws;            // [2048][2048]
  bf16* wo_s  = kws;            // [2048][2048] (post-attn)

  const int N8X = M_ * D_ / 8;   // 1048576
  const int N8W = D_ * D_ / 8;   // 524288

  dim3 bb(256);
  cvt_f32_bf16<<<N8X / 256, bb, 0, stream>>>(x, xbf, N8X);
  cvt_f32_bf16<<<N8W / 256, bb, 0, stream>>>(Wq, wqk, N8W);
  cvt_f32_bf16<<<N8W / 256, bb, 0, stream>>>(Wk, wqk + WN, N8W);

  // QK fused: N=4096, grid 32x32 = 1024 blocks
  gemm_bt<0, bf16><<<dim3(32, 32), bb, 0, stream>>>(xbf, wqk, bq, bk, qws, kws);

  cvt_f32_bf16<<<N8W / 256, bb, 0, stream>>>(Wv, wv_s, N8W);
  gemm_bt<2, bf16><<<dim3(16, 32), bb, 0, stream>>>(xbf, wv_s, bv, bv, vtw, vtw);

  attn_fused<<<dim3(S_ / QBLK, B_ * H_), dim3(512), 0, stream>>>(qws, kws, vtw, aws);

  cvt_f32_bf16<<<N8W / 256, bb, 0, stream>>>(Wo, wo_s, N8W);
  gemm_bt<3, float><<<dim3(16, 32), bb, 0, stream>>>(aws, wo_s, bo, bo, out, out);
}

// Round 5
// 452.092 us; speedup vs baseline: 1.7773x; 1.7773x over previous
//
#include <hip/hip_runtime.h>
#include <hip/hip_bf16.h>

#define B_  2
#define S_  2048
#define D_  2048
#define H_  16
#define DH_ 128
#define M_  (B_*S_)   // 4096

typedef __hip_bfloat16 bf16;
typedef float v4f __attribute__((ext_vector_type(4)));
typedef short v8s __attribute__((ext_vector_type(8)));

__device__ __forceinline__ short f2s(float x) {
  bf16 h = __float2bfloat16(x);
  return *reinterpret_cast<const short*>(&h);
}
// load 8 contiguous f32 elems, convert to bf16 bits
__device__ __forceinline__ v8s ld8(const float* p) {
  v4f a = *reinterpret_cast<const v4f*>(p);
  v4f b = *reinterpret_cast<const v4f*>(p + 4);
  v8s r = { f2s(a[0]), f2s(a[1]), f2s(a[2]), f2s(a[3]),
            f2s(b[0]), f2s(b[1]), f2s(b[2]), f2s(b[3]) };
  return r;
}
__device__ __forceinline__ void store_out(bf16* p, float v)  { *p = __float2bfloat16(v); }
__device__ __forceinline__ void store_out(float* p, float v) { *p = v; }

// async 16B global->LDS (direct, no VGPR round-trip). LDS dest is
// wave-uniform base + lane*16; global src is per-lane.
__device__ __forceinline__ void gll16(const bf16* g, bf16* l) {
  __builtin_amdgcn_global_load_lds((const __attribute__((address_space(1))) void*)g,
                                   (__attribute__((address_space(3))) void*)l,
                                   16, 0, 0);
}

// streaming f32 -> bf16 convert, 8 elems/thread
__global__ __launch_bounds__(256) void cvt_f32_bf16(const float* __restrict__ in,
                                                    bf16* __restrict__ out, int n8) {
  int i = blockIdx.x * 256 + threadIdx.x;
  if (i >= n8) return;
  *reinterpret_cast<v8s*>(out + (size_t)i * 8) = ld8(in + (size_t)i * 8);
}

// C = A @ W^T + bias ; A [M,K] bf16 row-major, W [N,K] bf16 row-major.
// 128x128 tile, BK=64 (one barrier-drain per 32 MFMAs), single-buffered LDS
// (32 KiB -> 2 blocks/CU TLP preserved), global_load_lds width-16 staging.
// LDS [128][64] rows are 128 B -> 16-way bank conflict unswizzled; so both
// sides XOR-swizzled (rule 21): stored 16B-block c' = c ^ (row&7) via the
// pre-swizzled GLOBAL source; reads use block (cb ^ (l16&7)). Same pattern
// as the attn K staging (verified since round 2).
// MODE 0: QK fused, W=[Wq;Wk] (N=4096). n<2048 -> Q (scaled) else K, both
//         to [B,H,S,dh].
// MODE 2: V -> [B,H,dh,S]  (transposed for PV fragment loads)
// MODE 3: plain [M,N] f32 out (final projection)
template <int MODE, typename TOUT>
__global__ __launch_bounds__(256) void gemm_bt(const bf16* __restrict__ A,
                                               const bf16* __restrict__ W,
                                               const float* __restrict__ bias0,
                                               const float* __restrict__ bias1,
                                               TOUT* __restrict__ out0,
                                               TOUT* __restrict__ out1) {
  __shared__ __align__(16) bf16 As[128 * 64];
  __shared__ __align__(16) bf16 Bs[128 * 64];
  const int tid  = threadIdx.x;
  const int lane = tid & 63, wave = tid >> 6;
  const int wm = wave >> 1, wn = wave & 1;
  const int quad = lane >> 4, l16 = lane & 15;
  const int swz  = l16 & 7;
  const int bm = blockIdx.y * 128, bn = blockIdx.x * 128;

  const bf16* Arow = A + (size_t)bm * D_;
  const bf16* Wrow = W + (size_t)bn * D_;

  // staging geometry: 128 rows x 8 16B-blocks = 1024 blocks per matrix;
  // 4 rounds of 256 threads. blk = j*256+tid: row=blk>>3, col-block=blk&7.
  // LDS linear dest (row*64 + c*8 elems) == blk*8 -> wave-uniform base
  // j*2048 + wave*512; global source col pre-swizzled.
  v4f acc[4][4] = {};
  for (int k0 = 0; k0 < D_; k0 += 64) {
#pragma unroll
    for (int j = 0; j < 4; ++j) {
      const int blk = j * 256 + tid;
      const int row = blk >> 3, c = blk & 7;
      const int gcol = k0 + (((c ^ (row & 7)) << 3));
      gll16(Arow + (size_t)row * D_ + gcol, As + j * 2048 + wave * 512);
      gll16(Wrow + (size_t)row * D_ + gcol, Bs + j * 2048 + wave * 512);
    }
    __syncthreads();   // compiler drains vmcnt before s_barrier
    v8s af[4][2], bfr[4][2];
#pragma unroll
    for (int mi = 0; mi < 4; ++mi)
#pragma unroll
      for (int kk = 0; kk < 2; ++kk)
        af[mi][kk] = *reinterpret_cast<const v8s*>(
            &As[(wm * 64 + mi * 16 + l16) * 64 + (((kk * 4 + quad) ^ swz) << 3)]);
#pragma unroll
    for (int ni = 0; ni < 4; ++ni)
#pragma unroll
      for (int kk = 0; kk < 2; ++kk)
        bfr[ni][kk] = *reinterpret_cast<const v8s*>(
            &Bs[(wn * 64 + ni * 16 + l16) * 64 + (((kk * 4 + quad) ^ swz) << 3)]);
#pragma unroll
    for (int kk = 0; kk < 2; ++kk)
#pragma unroll
      for (int mi = 0; mi < 4; ++mi)
#pragma unroll
        for (int ni = 0; ni < 4; ++ni)
          acc[mi][ni] = __builtin_amdgcn_mfma_f32_16x16x32_bf16(
              af[mi][kk], bfr[ni][kk], acc[mi][ni], 0, 0, 0);
    __syncthreads();
  }

  constexpr float QSCALE = 0.12752003912f;  // 1/sqrt(128) * log2(e)
  const int proj = (MODE == 0) ? (bn >> 11) : 0;   // block-uniform: 0=Q, 1=K
  const float* bias = proj ? bias1 : bias0;
  TOUT* outp = proj ? out1 : out0;
  const int bnl = bn & 2047;
#pragma unroll
  for (int ni = 0; ni < 4; ++ni) {
    const int nl = bnl + wn * 64 + ni * 16 + l16;   // 0..2047 within projection
    const float bv = bias[nl];
#pragma unroll
    for (int mi = 0; mi < 4; ++mi) {
      const int m0 = bm + wm * 64 + mi * 16 + quad * 4;
#pragma unroll
      for (int r = 0; r < 4; ++r) {
        const int m = m0 + r;           // row m: (b,s). col nl: (h,d)
        float v = acc[mi][ni][r] + bv;
        size_t idx;
        if (MODE == 0) {
          if (!proj) v *= QSCALE;
          int b = m >> 11, s = m & (S_ - 1);
          int h = nl >> 7, d = nl & (DH_ - 1);
          idx = ((size_t)(b * H_ + h) * S_ + s) * DH_ + d;
        } else if (MODE == 2) {
          int b = m >> 11, s = m & (S_ - 1);
          int h = nl >> 7, d = nl & (DH_ - 1);
          idx = ((size_t)(b * H_ + h) * DH_ + d) * S_ + s;
        } else {
          idx = (size_t)m * D_ + nl;
        }
        store_out(outp + idx, v);
      }
    }
  }
}

// Flash attention, causal. Q/K: [B,H,S,dh], Vt: [B,H,dh,S] (all bf16). Out: [B,S,D] bf16.
// Block = 128 Q rows (8 waves x 16 rows), K-tile = 64 keys, 512 threads.
// Round-2 verified configuration (149.7 us): single-buffered K/V staged via
// global_load_lds with XOR-swizzled GLOBAL source; reads apply the same XOR.
#define QBLK 128
__global__ __launch_bounds__(512, 4) void attn_fused(const bf16* __restrict__ Q,
                                                     const bf16* __restrict__ K,
                                                     const bf16* __restrict__ Vt,
                                                     bf16* __restrict__ Oa) {
  __shared__ __align__(16) bf16 Ks[64 * 128];   // [key][d] linear; blk c holds global c^(key&7)
  __shared__ __align__(16) bf16 Vs[128 * 64];   // [d][key] linear; blk c holds global c^(d&7)
  __shared__ __align__(16) bf16 Ps[8][16 * 72]; // per-wave P, padded stride 72
  const int tid  = threadIdx.x;
  const int lane = tid & 63, wave = tid >> 6;
  const int quad = lane >> 4, l16 = lane & 15;
  const int swz  = l16 & 7;
  // longest-first: work per block ~ qt, launch big blocks first.
  const int qt = (int)gridDim.x - 1 - (int)blockIdx.x;
  const int bh = blockIdx.y;
  const int b = bh >> 4, h = bh & 15;
  const bf16* Qh = Q  + (size_t)bh * S_ * DH_;
  const bf16* Kh = K  + (size_t)bh * S_ * DH_;
  const bf16* Vh = Vt + (size_t)bh * DH_ * S_;

  const int qrow0 = qt * QBLK + wave * 16;
  v8s qf[4];
#pragma unroll
  for (int kk = 0; kk < 4; ++kk)
    qf[kk] = *reinterpret_cast<const v8s*>(&Qh[(size_t)(qrow0 + l16) * DH_ + kk * 32 + quad * 8]);

  v4f acc_o[8] = {};
  float m_i[4], l_i[4];
#pragma unroll
  for (int r = 0; r < 4; ++r) { m_i[r] = -1.0e30f; l_i[r] = 0.f; }

  const int nkt = 2 * qt + 2;
  for (int kt = 0; kt < nkt; ++kt) {
    const int kbase = kt * 64;
    // --- stage K (64x256B) and V (128x128B) via global_load_lds, 2 rounds ---
#pragma unroll
    for (int rr = 0; rr < 2; ++rr) {
      const int g = rr * 512 + tid;
      const int krow = g >> 4, kc = g & 15;           // K: 16 x 16B blocks/row
      gll16(Kh + (size_t)(kbase + krow) * DH_ + ((kc ^ (krow & 7)) << 3),
            Ks + rr * 4096 + wave * 512);
      const int vrow = g >> 3, vc = g & 7;            // V: 8 x 16B blocks/row
      gll16(Vh + (size_t)vrow * S_ + kbase + ((vc ^ (vrow & 7)) << 3),
            Vs + rr * 4096 + wave * 512);
    }
    __syncthreads();   // drains vmcnt (gll16) + all waves staged

    const bool active = (kbase <= qrow0 + 15);
    if (active) {
      // S = Q K^T (Q pre-scaled by 1/sqrt(dh)*log2e)
      v4f sc[4];
      __builtin_amdgcn_s_setprio(1);
#pragma unroll
      for (int nt = 0; nt < 4; ++nt) {
        v4f a = {};
#pragma unroll
        for (int kk = 0; kk < 4; ++kk) {
          v8s kf = *reinterpret_cast<const v8s*>(
              &Ks[(nt * 16 + l16) * 128 + (((kk * 4 + quad) ^ swz) << 3)]);
          a = __builtin_amdgcn_mfma_f32_16x16x32_bf16(qf[kk], kf, a, 0, 0, 0);
        }
        sc[nt] = a;
      }
      __builtin_amdgcn_s_setprio(0);
      if (kbase + 63 > qrow0) {   // diagonal tile: causal mask
#pragma unroll
        for (int nt = 0; nt < 4; ++nt)
#pragma unroll
          for (int r = 0; r < 4; ++r) {
            int kc2 = kbase + nt * 16 + l16;
            int qr = qrow0 + quad * 4 + r;
            if (kc2 > qr) sc[nt][r] = -1.0e30f;
          }
      }
      // online softmax; C-layout: row = quad*4 + r, col = nt*16 + l16
#pragma unroll
      for (int r = 0; r < 4; ++r) {
        float mx = fmaxf(fmaxf(sc[0][r], sc[1][r]), fmaxf(sc[2][r], sc[3][r]));
        mx = fmaxf(mx, __shfl_xor(mx, 1));
        mx = fmaxf(mx, __shfl_xor(mx, 2));
        mx = fmaxf(mx, __shfl_xor(mx, 4));
        mx = fmaxf(mx, __shfl_xor(mx, 8));
        // T13 defer-max: only rescale when max grew by >8 (log2 domain)
        if (mx > m_i[r] + 8.0f) {
          float alpha = exp2f(m_i[r] - mx);
          m_i[r] = mx;
          l_i[r] *= alpha;
#pragma unroll
          for (int nt8 = 0; nt8 < 8; ++nt8) acc_o[nt8][r] *= alpha;
        }
        const float mm = m_i[r];
        float s0 = exp2f(sc[0][r] - mm);
        float s1 = exp2f(sc[1][r] - mm);
        float s2 = exp2f(sc[2][r] - mm);
        float s3 = exp2f(sc[3][r] - mm);
        sc[0][r] = s0; sc[1][r] = s1; sc[2][r] = s2; sc[3][r] = s3;
        float t = s0 + s1 + s2 + s3;
        t += __shfl_xor(t, 1); t += __shfl_xor(t, 2);
        t += __shfl_xor(t, 4); t += __shfl_xor(t, 8);
        l_i[r] += t;
      }
      // P: C-layout regs -> per-wave LDS (bf16) -> A-layout frags
#pragma unroll
      for (int nt = 0; nt < 4; ++nt)
#pragma unroll
        for (int r = 0; r < 4; ++r)
          Ps[wave][(quad * 4 + r) * 72 + nt * 16 + l16] = __float2bfloat16(sc[nt][r]);
      // own-wave write->read ordering only; no cross-wave dep -> no barrier
      asm volatile("s_waitcnt lgkmcnt(0)" ::: "memory");
      // O += P V
      __builtin_amdgcn_s_setprio(1);
#pragma unroll
      for (int kk2 = 0; kk2 < 2; ++kk2) {
        v8s pf = *reinterpret_cast<const v8s*>(&Ps[wave][l16 * 72 + kk2 * 32 + quad * 8]);
#pragma unroll
        for (int nt8 = 0; nt8 < 8; ++nt8) {
          v8s vf = *reinterpret_cast<const v8s*>(
              &Vs[(nt8 * 16 + l16) * 64 + (((kk2 * 4 + quad) ^ swz) << 3)]);
          acc_o[nt8] = __builtin_amdgcn_mfma_f32_16x16x32_bf16(pf, vf, acc_o[nt8], 0, 0, 0);
        }
      }
      __builtin_amdgcn_s_setprio(0);
    }
    __syncthreads();   // Ks/Vs consumed; safe to restage
  }

#pragma unroll
  for (int r = 0; r < 4; ++r) {
    const float inv = 1.0f / l_i[r];
    const int srow = qrow0 + quad * 4 + r;
#pragma unroll
    for (int nt8 = 0; nt8 < 8; ++nt8)
      Oa[((size_t)b * S_ + srow) * D_ + h * DH_ + nt8 * 16 + l16] =
          __float2bfloat16(acc_o[nt8][r] * inv);
  }
}

extern "C" void kernel_launch(void* const* d_in, const int* in_sizes, int n_in,
                              void* d_out, int out_size, void* d_ws, size_t ws_size,
                              hipStream_t stream) {
  // Canary: all-zero output (absmax exactly 3.5625) signals a tripped assumption.
  if (n_in != 9 ||
      in_sizes[0] != M_ * D_ ||
      in_sizes[1] != D_ * D_ || in_sizes[2] != D_ ||
      in_sizes[3] != D_ * D_ || in_sizes[4] != D_ ||
      in_sizes[5] != D_ * D_ || in_sizes[6] != D_ ||
      in_sizes[7] != D_ * D_ || in_sizes[8] != D_ ||
      out_size != M_ * D_)
    return;

  const float* x  = (const float*)d_in[0];
  const float* Wq = (const float*)d_in[1];
  const float* bq = (const float*)d_in[2];
  const float* Wk = (const float*)d_in[3];
  const float* bk = (const float*)d_in[4];
  const float* Wv = (const float*)d_in[5];
  const float* bv = (const float*)d_in[6];
  const float* Wo = (const float*)d_in[7];
  const float* bo = (const float*)d_in[8];
  float* out = (float*)d_out;   // OUTPUT IS FLOAT32 (reference output dtype)

  const size_t NT = (size_t)M_ * D_;   // 8388608 elems per tensor
  const size_t WN = (size_t)D_ * D_;   // 4194304 elems per weight
  // Buffer plan:
  //   d_out (33.6 MB f32):  [0,16.8) qws (bf16 Q), [16.8,33.6) x_bf16
  //     both dead before the final GEMM overwrites d_out.
  //   ws (50.3 MB): kws | vtw | aws
  //     Wq||Wk concat (16.8 MB) fills aws before the QK GEMM; Wv reuses
  //     aws[0:8.4) before the V GEMM; aws becomes the attn output after
  //     (weights dead); Wo parks in kws (K dead after attn).
  bf16* qws   = (bf16*)d_out;
  bf16* xbf   = (bf16*)d_out + NT;
  bf16* kws   = (bf16*)d_ws;
  bf16* vtw   = kws + NT;
  bf16* aws   = vtw + NT;
  bf16* wqk   = aws;            // [4096][2048] bf16 concat
  bf16* wv_s  = aws;            // [2048][2048]
  bf16* wo_s  = kws;            // [2048][2048] (post-attn)

  const int N8X = M_ * D_ / 8;   // 1048576
  const int N8W = D_ * D_ / 8;   // 524288

  dim3 bb(256);
  cvt_f32_bf16<<<N8X / 256, bb, 0, stream>>>(x, xbf, N8X);
  cvt_f32_bf16<<<N8W / 256, bb, 0, stream>>>(Wq, wqk, N8W);
  cvt_f32_bf16<<<N8W / 256, bb, 0, stream>>>(Wk, wqk + WN, N8W);

  // QK fused: N=4096, grid 32x32 = 1024 blocks
  gemm_bt<0, bf16><<<dim3(32, 32), bb, 0, stream>>>(xbf, wqk, bq, bk, qws, kws);

  cvt_f32_bf16<<<N8W / 256, bb, 0, stream>>>(Wv, wv_s, N8W);
  gemm_bt<2, bf16><<<dim3(16, 32), bb, 0, stream>>>(xbf, wv_s, bv, bv, vtw, vtw);

  attn_fused<<<dim3(S_ / QBLK, B_ * H_), dim3(512), 0, stream>>>(qws, kws, vtw, aws);

  cvt_f32_bf16<<<N8W / 256, bb, 0, stream>>>(Wo, wo_s, N8W);
  gemm_bt<3, float><<<dim3(16, 32), bb, 0, stream>>>(aws, wo_s, bo, bo, out, out);
}